// Round 2
// baseline (141.272 us; speedup 1.0000x reference)
//
#include <hip/hip_runtime.h>

// Rowwise cosine similarity: out[r] = dot(a_r,b_r) * rsqrt(max(|a_r|^2,eps)) * rsqrt(max(|b_r|^2,eps))
// a, b: [16, 4096, 256] f32 contiguous -> 65536 rows of 256 floats.
//
// Each 64-lane wave handles 4 rows via 16-lane groups:
//   lane = grp*16 + sub;  row = blockBase + wave*4 + grp
//   lane loads float4 at positions sub, sub+16, sub+32, sub+48 of its row
//   (16 lanes x 4 float4 x 4 floats = 256 = full row), for both a and b.
// 8 outstanding 16B loads per lane -> good memory-level parallelism.
// Reduction: 4-step shfl_xor butterfly within 16-lane groups (width 16).
// The wave's 4 output dwords are contiguous -> single store transaction.

#define D 256
#define EPS 1e-12f

__global__ __launch_bounds__(256) void cosine_rows_kernel(
    const float* __restrict__ a,
    const float* __restrict__ b,
    float* __restrict__ out,
    int n_rows)
{
    const int lane = threadIdx.x & 63;
    const int wave = threadIdx.x >> 6;      // 4 waves per block
    const int sub  = lane & 15;             // position within 16-lane group
    const int grp  = lane >> 4;             // which of the wave's 4 rows
    const int row  = blockIdx.x * 16 + wave * 4 + grp;
    if (row >= n_rows) return;

    const float4* a4 = reinterpret_cast<const float4*>(a + (size_t)row * D);
    const float4* b4 = reinterpret_cast<const float4*>(b + (size_t)row * D);

    // Issue all 8 loads before any use.
    float4 av0 = a4[sub];
    float4 av1 = a4[sub + 16];
    float4 av2 = a4[sub + 32];
    float4 av3 = a4[sub + 48];
    float4 bv0 = b4[sub];
    float4 bv1 = b4[sub + 16];
    float4 bv2 = b4[sub + 32];
    float4 bv3 = b4[sub + 48];

    float sa = 0.f, sb = 0.f, sab = 0.f;
    #define ACC(av, bv)                                          \
        sa  += av.x*av.x + av.y*av.y + av.z*av.z + av.w*av.w;    \
        sb  += bv.x*bv.x + bv.y*bv.y + bv.z*bv.z + bv.w*bv.w;    \
        sab += av.x*bv.x + av.y*bv.y + av.z*bv.z + av.w*bv.w;
    ACC(av0, bv0)
    ACC(av1, bv1)
    ACC(av2, bv2)
    ACC(av3, bv3)
    #undef ACC

    // Butterfly within each 16-lane group.
    #pragma unroll
    for (int off = 8; off > 0; off >>= 1) {
        sa  += __shfl_xor(sa,  off, 16);
        sb  += __shfl_xor(sb,  off, 16);
        sab += __shfl_xor(sab, off, 16);
    }

    if (sub == 0) {
        out[row] = sab * rsqrtf(fmaxf(sa, EPS)) * rsqrtf(fmaxf(sb, EPS));
    }
}

extern "C" void kernel_launch(void* const* d_in, const int* in_sizes, int n_in,
                              void* d_out, int out_size, void* d_ws, size_t ws_size,
                              hipStream_t stream)
{
    const float* a = (const float*)d_in[0];
    const float* b = (const float*)d_in[1];
    float* out = (float*)d_out;

    const int n_rows = out_size;             // 16 * 4096 = 65536
    const int rows_per_block = 16;           // 4 waves x 4 rows
    const int grid = (n_rows + rows_per_block - 1) / rows_per_block;

    cosine_rows_kernel<<<grid, 256, 0, stream>>>(a, b, out, n_rows);
}